// Round 4
// baseline (623.360 us; speedup 1.0000x reference)
//
#include <hip/hip_runtime.h>

// (B,T,C,H) = (8,2048,1024,16), D=64
#define Tdim 2048

typedef __attribute__((ext_vector_type(8))) short bf16x8;
typedef __attribute__((ext_vector_type(16))) float f32x16;
typedef __attribute__((ext_vector_type(4))) short short4v;

#define GLOBAL_U32(p) ((const __attribute__((address_space(1))) unsigned int*)(p))
#define LDS_U32(p)    ((__attribute__((address_space(3))) unsigned int*)(p))

__device__ __forceinline__ float phi_f(float x) {
    return x > 0.f ? (x + 1.f) : __expf(x);
}
// round-to-nearest-even fp32 -> bf16 (finite inputs only)
__device__ __forceinline__ short f2bf(float f) {
    unsigned u = __float_as_uint(f);
    u += 0x7fffu + ((u >> 16) & 1u);
    return (short)(u >> 16);
}
__device__ __forceinline__ float bf2f(short h) {
    return __uint_as_float(((unsigned)(unsigned short)h) << 16);
}

// ===========================================================================
// TILED32 layout (for v_mfma_f32_32x32x16_bf16): matrix [R x K] bf16 stored
// as tiles of 32 rows x 16 k.  Tile (rt, kt) at ((rt*(K/16))+kt)*512 shorts;
// slot L (0..63) holds row rt*32+(L&31), k = kt*16+(L>>5)*8 .. +8.  One wave
// staging instr = 1 KB contiguous; fragment read = tile_base + lane*16B
// (conflict-free identity).  A-frag: row=lane&31, k=(lane>>5)*8+e.
// C/D frag: col=lane&31, row=(reg&3)+8*(reg>>2)+4*(lane>>5).
//
// Y-SCRATCH (GEMM2's A): same tiles embedded in the dead k/v region of qkv.
// Tile (RT, kt, plane) at physical row RT*32 + hh*2 + ((kt&3)>>1) where
// hh = kt>>2, shorts offset 2048 + ((kt&1)*2 + plane)*512.  1 KB contiguous.
// ===========================================================================

// ---------------------------------------------------------------------------
// x [16384 x 1024] fp32 -> tiled32 split hi/lo. Block: 32 rows x 64 cols.
// ---------------------------------------------------------------------------
__global__ __launch_bounds__(256) void split_tile_kernel(
    const float* __restrict__ X, short* __restrict__ Hi, short* __restrict__ Lo)
{
    const int rt = blockIdx.x;          // row-tile 0..511 (32 rows)
    const int cb = blockIdx.y;          // col-block 0..15 (64 cols)
    const int t = threadIdx.x;
    const int r = t & 31;               // row in tile
    const int c = t >> 5;               // col-chunk (8 cols) 0..7

    const float* xp = X + ((size_t)rt * 32 + r) * 1024 + cb * 64 + c * 8;
    const float4 a = *(const float4*)xp;
    const float4 b = *(const float4*)(xp + 4);
    float v[8] = {a.x, a.y, a.z, a.w, b.x, b.y, b.z, b.w};
    bf16x8 h, l;
#pragma unroll
    for (int j = 0; j < 8; ++j) {
        const short hh = f2bf(v[j]);
        h[j] = hh;
        l[j] = f2bf(v[j] - bf2f(hh));
    }
    const int kt = cb * 4 + (c >> 1);   // k-tile (16 k) 0..63
    const int slot = ((c & 1) << 5) | r;
    const size_t off = ((size_t)rt * 64 + kt) * 512 + slot * 8;
    *(bf16x8*)(Hi + off) = h;
    *(bf16x8*)(Lo + off) = l;
}

// ---------------------------------------------------------------------------
// W [1024 x N] fp32 -> W^T [N x 1024] tiled32 split hi/lo. One wave per tile.
// nkt = 1024/16 = 64 (hardcoded).
// ---------------------------------------------------------------------------
__global__ __launch_bounds__(256) void w_tile_kernel(
    const float* __restrict__ W, int N,
    short* __restrict__ Thi, short* __restrict__ Tlo)
{
    const int tile = blockIdx.x * 4 + (threadIdx.x >> 6);
    const int nt = tile >> 6;           // n-tile (32 cols of W)
    const int kt = tile & 63;           // k-tile (16 rows of W)
    const int lane = threadIdx.x & 63;
    const int n = nt * 32 + (lane & 31);
    const int k = kt * 16 + (lane >> 5) * 8;
    const float* wp = W + (size_t)k * N + n;
    bf16x8 h, l;
#pragma unroll
    for (int j = 0; j < 8; ++j) {
        const float v = wp[(size_t)j * N];
        const short hh = f2bf(v);
        h[j] = hh;
        l[j] = f2bf(v - bf2f(hh));
    }
    const size_t off = (size_t)tile * 512 + lane * 8;
    *(bf16x8*)(Thi + off) = h;
    *(bf16x8*)(Tlo + off) = l;
}

// ---------------------------------------------------------------------------
// bf16x3 split-precision GEMM: C = (Ahi+Alo)[M,K] * (Bhi+Blo)^T[N,K] + bias
// (drops lo*lo), 32x32x16 MFMA (2495 TF rate vs 2075 for 16x16x32).
//
// 256x256 block tile, BK=32 (2 k-subtiles), 8 waves (2m x 4n), per-wave
// output 128x64 = 4x2 tiles of 32x32.  48 MFMA/wave/K-step, same 24 KB LDS
// reads/wave/K-step as the 16x16 version.  Double-buffered LDS (2x64 KiB),
// 2-phase pipeline (round-1 proven): stage next K-step before compute,
// single barrier per K-step, setprio(1) around MFMA cluster.
//
// B always TILED32.  AMODE 0: A TILED32.  AMODE 2: A = y-scratch tiles in
// qkv (see header).  Fragment read = identity lane*8 for both.  K = 1024.
// ---------------------------------------------------------------------------
template<int AMODE>
__global__ __launch_bounds__(512, 2) void gemm3_kernel(
    const short* __restrict__ Ahi, const short* __restrict__ Alo, int lda,
    const short* __restrict__ BThi, const short* __restrict__ BTlo,
    const float* __restrict__ bias, float* __restrict__ C,
    int K, int ldc)
{
    // [2 buf][4 arrays][16 tiles][512 shorts] = 128 KiB
    __shared__ short smem[65536];
    const int tid = threadIdx.x;
    const int lane = tid & 63;
    const int wid = tid >> 6;            // wave 0..7
    const int bx = blockIdx.x, by = blockIdx.y;
    const int wm = wid >> 2, wn = wid & 3;

    const size_t tilestep = (size_t)(K >> 4) * 512;   // shorts per 32-row-tile

    // staging: wave w stages 8 tiles of array sel (0:Ahi 1:Alo 2:Bhi 3:Blo),
    // half h: row-tiles h*4 .. h*4+3, both k-subtiles of the K-step.
    // tile c (0..7): rtl = h*4 + (c>>1), ktl = c&1.
    const int sel = wid >> 1, half = wid & 1;
    const short* gptr;
    if (sel >= 2) {
        const short* gb = (sel == 2) ? BThi : BTlo;
        gptr = gb + (size_t)(bx * 8 + half * 4) * tilestep + lane * 8;
    } else if (AMODE == 0) {
        const short* gb = (sel == 0) ? Ahi : Alo;
        gptr = gb + (size_t)(by * 8 + half * 4) * tilestep + lane * 8;
    } else {
        // AMODE 2: y-scratch tiles in qkv; row stride 6144 shorts.
        gptr = Ahi + (size_t)((by * 8 + half * 4) * 32) * 6144 + 2048
                   + sel * 512 + lane * 8;
    }
    // wave-uniform LDS dest base (buffer 0); wave's 8 tiles contiguous:
    // LDS tile idx within array = rtl*2 + ktl = half*8 + c
    short* lw = smem + sel * 8192 + half * 4096;

    f32x16 acc[4][2];
#pragma unroll
    for (int i = 0; i < 4; ++i)
#pragma unroll
        for (int j = 0; j < 2; ++j)
#pragma unroll
            for (int r = 0; r < 16; ++r) acc[i][j][r] = 0.f;

    auto stage = [&](int buf, int k0) {
        short* lb = lw + buf * 32768;
        if (AMODE == 0 || sel >= 2) {
            const short* g = gptr + (size_t)(k0 >> 4) * 512;
#pragma unroll
            for (int c = 0; c < 8; ++c)
                __builtin_amdgcn_global_load_lds(
                    GLOBAL_U32(g + (size_t)(c >> 1) * tilestep + (c & 1) * 512),
                    LDS_U32(lb + c * 512), 16, 0, 0);
        } else {
            // physical row advances by k0>>5 per K-step (kt0 even)
            const short* g = gptr + (size_t)(k0 >> 5) * 6144;
#pragma unroll
            for (int c = 0; c < 8; ++c)
                __builtin_amdgcn_global_load_lds(
                    GLOBAL_U32(g + (size_t)((c >> 1) * 32) * 6144 + (c & 1) * 1024),
                    LDS_U32(lb + c * 512), 16, 0, 0);
        }
    };

    // prologue: fill buffer 0 (syncthreads drains vmcnt before s_barrier)
    stage(0, 0);
    __syncthreads();

    const int fo = lane * 8;
    int cur = 0;
    for (int k0 = 0; k0 < K; k0 += 32) {
        if (k0 + 32 < K) stage(cur ^ 1, k0 + 32);   // prefetch next K-step

        const short* bp = smem + cur * 32768;
        bf16x8 bh[2][2], bl[2][2];
#pragma unroll
        for (int j = 0; j < 2; ++j)
#pragma unroll
            for (int s = 0; s < 2; ++s) {
                const int ti = ((wn * 2 + j) * 2 + s) * 512;
                bh[j][s] = *(const bf16x8*)(bp + 16384 + ti + fo);
                bl[j][s] = *(const bf16x8*)(bp + 24576 + ti + fo);
            }
        __builtin_amdgcn_s_setprio(1);
#pragma unroll
        for (int i = 0; i < 4; ++i) {
            const int ai = ((wm * 4 + i) * 2) * 512;
            const bf16x8 ah0 = *(const bf16x8*)(bp + ai + fo);
            const bf16x8 ah1 = *(const bf16x8*)(bp + ai + 512 + fo);
            const bf16x8 al0 = *(const bf16x8*)(bp + 8192 + ai + fo);
            const bf16x8 al1 = *(const bf16x8*)(bp + 8192 + ai + 512 + fo);
#pragma unroll
            for (int j = 0; j < 2; ++j) {
                acc[i][j] = __builtin_amdgcn_mfma_f32_32x32x16_bf16(ah0, bh[j][0], acc[i][j], 0, 0, 0);
                acc[i][j] = __builtin_amdgcn_mfma_f32_32x32x16_bf16(al0, bh[j][0], acc[i][j], 0, 0, 0);
                acc[i][j] = __builtin_amdgcn_mfma_f32_32x32x16_bf16(ah0, bl[j][0], acc[i][j], 0, 0, 0);
                acc[i][j] = __builtin_amdgcn_mfma_f32_32x32x16_bf16(ah1, bh[j][1], acc[i][j], 0, 0, 0);
                acc[i][j] = __builtin_amdgcn_mfma_f32_32x32x16_bf16(al1, bh[j][1], acc[i][j], 0, 0, 0);
                acc[i][j] = __builtin_amdgcn_mfma_f32_32x32x16_bf16(ah1, bl[j][1], acc[i][j], 0, 0, 0);
            }
        }
        __builtin_amdgcn_s_setprio(0);
        __syncthreads();
        cur ^= 1;
    }

    // epilogue: 32x32 C/D layout col=lane&31, row=(reg&3)+8*(reg>>2)+4*(lane>>5)
    const int fc = lane & 31, fq = lane >> 5;
#pragma unroll
    for (int i = 0; i < 4; ++i) {
#pragma unroll
        for (int j = 0; j < 2; ++j) {
            const int col = bx * 256 + wn * 64 + j * 32 + fc;
            const float bv = bias[col];
            const size_t row0 = (size_t)by * 256 + wm * 128 + i * 32 + fq * 4;
            float* cp = C + row0 * (size_t)ldc + col;
#pragma unroll
            for (int r = 0; r < 16; ++r) {
                const int rr = (r & 3) + 8 * (r >> 2);
                cp[(size_t)rr * ldc] = acc[i][j][r] + bv;
            }
        }
    }
}

// ---------------------------------------------------------------------------
// Partial kv/ksum per (T-chunk, bh): 8 x 128 = 1024 blocks.
// ---------------------------------------------------------------------------
__global__ __launch_bounds__(256) void kv_part_kernel(
    const float* __restrict__ qkv, const int* __restrict__ attn,
    float* __restrict__ kvpart, float* __restrict__ kspart)
{
    __shared__ float ks[32][64];
    __shared__ float vs[32][64];

    const int chunk = blockIdx.x;       // 0..7
    const int bh = blockIdx.y;          // 0..127
    const int b = bh >> 4;
    const int h = bh & 15;
    const int tid = threadIdx.x;
    const int tx = tid & 15;
    const int ty = tid >> 4;
    const int l_t = tid >> 4;
    const int l_d = (tid & 15) << 2;

    const float* kb = qkv + (size_t)b * Tdim * 3072 + 1024 + h * 64;
    const float* vb = qkv + (size_t)b * Tdim * 3072 + 2048 + h * 64;
    const int* am = attn + b * Tdim;

    float acc[4][4];
#pragma unroll
    for (int i = 0; i < 4; ++i)
#pragma unroll
        for (int j = 0; j < 4; ++j) acc[i][j] = 0.f;
    float ksl = 0.f;

    for (int t0 = chunk * 256; t0 < (chunk + 1) * 256; t0 += 32) {
        __syncthreads();
#pragma unroll
        for (int rr = 0; rr < 2; ++rr) {
            const int t = l_t + rr * 16;
            const int gt = t0 + t;
            const float m = (am[gt] > 0) ? 1.f : 0.f;
            const float4 k4 = *(const float4*)(kb + (size_t)gt * 3072 + l_d);
            const float4 v4 = *(const float4*)(vb + (size_t)gt * 3072 + l_d);
            float4 kp, vp;
            kp.x = phi_f(k4.x) * m; kp.y = phi_f(k4.y) * m;
            kp.z = phi_f(k4.z) * m; kp.w = phi_f(k4.w) * m;
            vp.x = v4.x * m; vp.y = v4.y * m; vp.z = v4.z * m; vp.w = v4.w * m;
            *(float4*)&ks[t][l_d] = kp;
            *(float4*)&vs[t][l_d] = vp;
        }
        __syncthreads();
#pragma unroll
        for (int t = 0; t < 32; ++t) {
            float kr[4], vr[4];
            *(float4*)kr = *(const float4*)&ks[t][ty * 4];
            *(float4*)vr = *(const float4*)&vs[t][tx * 4];
#pragma unroll
            for (int i = 0; i < 4; ++i)
#pragma unroll
                for (int j = 0; j < 4; ++j)
                    acc[i][j] = fmaf(kr[i], vr[j], acc[i][j]);
        }
        if (tid < 64) {
#pragma unroll
            for (int t = 0; t < 32; ++t) ksl += ks[t][tid];
        }
    }

    float* ko = kvpart + ((size_t)bh * 8 + chunk) * 4096;
#pragma unroll
    for (int i = 0; i < 4; ++i) {
        float4 o;
        o.x = acc[i][0]; o.y = acc[i][1]; o.z = acc[i][2]; o.w = acc[i][3];
        *(float4*)(ko + (ty * 4 + i) * 64 + tx * 4) = o;
    }
    if (tid < 64) kspart[((size_t)bh * 8 + chunk) * 64 + tid] = ksl;
}

__global__ __launch_bounds__(256) void kv_reduce_kernel(
    const float* __restrict__ kvpart, const float* __restrict__ kspart,
    float* __restrict__ kv, float* __restrict__ ksum)
{
    const int bh = blockIdx.x;
    const int tid = threadIdx.x;
    const float4* p = (const float4*)(kvpart + (size_t)bh * 8 * 4096);
    float4 s0 = {0,0,0,0}, s1 = {0,0,0,0}, s2 = {0,0,0,0}, s3 = {0,0,0,0};
#pragma unroll
    for (int c = 0; c < 8; ++c) {
        const int base = c * 1024;
        float4 a = p[base + tid], b = p[base + 256 + tid],
               cc = p[base + 512 + tid], d = p[base + 768 + tid];
        s0.x += a.x; s0.y += a.y; s0.z += a.z; s0.w += a.w;
        s1.x += b.x; s1.y += b.y; s1.z += b.z; s1.w += b.w;
        s2.x += cc.x; s2.y += cc.y; s2.z += cc.z; s2.w += cc.w;
        s3.x += d.x; s3.y += d.y; s3.z += d.z; s3.w += d.w;
    }
    float4* o = (float4*)(kv + (size_t)bh * 4096);
    o[tid] = s0; o[256 + tid] = s1; o[512 + tid] = s2; o[768 + tid] = s3;
    if (tid < 64) {
        float ss = 0.f;
#pragma unroll
        for (int c = 0; c < 8; ++c) ss += kspart[((size_t)bh * 8 + c) * 64 + tid];
        ksum[bh * 64 + tid] = ss;
    }
}

// ---------------------------------------------------------------------------
// y[t][f] = (phi(q[t])·kv[:,f]) / max(phi(q[t])·ksum, 1e-8).
// Writes y split hi/lo bf16 in TILED32 format into the dead k/v region of
// qkv: tile (RT, kt = hh*4 + ktl, plane p) at physical row
// RT*32 + hh*2 + (ktl>>1), shorts offset 2048 + ((ktl&1)*2 + p)*512.
// Disjoint across heads; never touches the q columns still being read.
// ---------------------------------------------------------------------------
__global__ __launch_bounds__(256) void attn_y_kernel(
    float* __restrict__ qkv, const float* __restrict__ kvin,
    const float* __restrict__ ksumin)
{
    __shared__ float qs[64][65];
    __shared__ float kvs[64][64];
    __shared__ float dinv[64];
    __shared__ float ksums[64];

    const int bh = blockIdx.y;
    const int b = bh >> 4;
    const int hh = bh & 15;
    const int t0 = blockIdx.x * 64;
    const int tid = threadIdx.x;
    const int tx = tid & 15;
    const int ty = tid >> 4;

    const float4* kvg = (const float4*)(kvin + (size_t)bh * 4096);
#pragma unroll
    for (int i = 0; i < 4; ++i)
        ((float4*)kvs)[tid + i * 256] = kvg[tid + i * 256];
    if (tid < 64) ksums[tid] = ksumin[bh * 64 + tid];

    float* qb = qkv + ((size_t)(b * Tdim + t0)) * 3072 + hh * 64;
#pragma unroll
    for (int rr = 0; rr < 4; ++rr) {
        const int t = (tid >> 4) + rr * 16;
        const int dd = (tid & 15) << 2;
        const float4 q4 = *(const float4*)(qb + (size_t)t * 3072 + dd);
        qs[t][dd + 0] = phi_f(q4.x);
        qs[t][dd + 1] = phi_f(q4.y);
        qs[t][dd + 2] = phi_f(q4.z);
        qs[t][dd + 3] = phi_f(q4.w);
    }
    __syncthreads();

    if (tid < 64) {
        float s = 0.f;
#pragma unroll
        for (int d = 0; d < 64; ++d) s = fmaf(qs[tid][d], ksums[d], s);
        dinv[tid] = 1.f / fmaxf(s, 1e-8f);
    }
    __syncthreads();

    float acc[4][4];
#pragma unroll
    for (int i = 0; i < 4; ++i)
#pragma unroll
        for (int j = 0; j < 4; ++j) acc[i][j] = 0.f;

#pragma unroll 4
    for (int d = 0; d < 64; ++d) {
        float qr[4];
        qr[0] = qs[ty * 4 + 0][d];
        qr[1] = qs[ty * 4 + 1][d];
        qr[2] = qs[ty * 4 + 2][d];
        qr[3] = qs[ty * 4 + 3][d];
        const float4 kr = *(const float4*)&kvs[d][tx * 4];
#pragma unroll
        for (int i = 0; i < 4; ++i) {
            acc[i][0] = fmaf(qr[i], kr.x, acc[i][0]);
            acc[i][1] = fmaf(qr[i], kr.y, acc[i][1]);
            acc[i][2] = fmaf(qr[i], kr.z, acc[i][2]);
            acc[i][3] = fmaf(qr[i], kr.w, acc[i][3]);
        }
    }

    // ---- tiled32 y-scratch write ----
    // thread covers rows t=ty*4+i (local 0..63), cols d=tx*4..tx*4+3.
    short* yb = (short*)qkv;
    const int d0 = tx * 4;
    const int ktl = d0 >> 4;            // k-tile within head (0..3)
    const int kg = (d0 >> 3) & 1;       // k-group within tile
    const int eb = d0 & 7;              // offset within 8-short group (0 or 4)
    const int prk = hh * 2 + (ktl >> 1);            // physical row key
    const size_t so = 2048 + (size_t)((ktl & 1) * 2) * 512;  // slot offset (hi)
#pragma unroll
    for (int i = 0; i < 4; ++i) {
        const int t = ty * 4 + i;
        const int grow = b * Tdim + t0 + t;
        const int RT = grow >> 5;
        const int rloc = grow & 31;
        const float di = dinv[t];
        short4v hv, lv;
#pragma unroll
        for (int j = 0; j < 4; ++j) {
            const float val = acc[i][j] * di;
            const short h = f2bf(val);
            hv[j] = h;
            lv[j] = f2bf(val - bf2f(h));
        }
        const size_t base = (size_t)(RT * 32 + prk) * 6144 + so
                          + (size_t)((kg << 5) | rloc) * 8 + eb;
        *(short4v*)(yb + base) = hv;          // plane 0 (hi)
        *(short4v*)(yb + base + 512) = lv;    // plane 1 (lo)
    }
}

// ---------------------------------------------------------------------------
extern "C" void kernel_launch(void* const* d_in, const int* in_sizes, int n_in,
                              void* d_out, int out_size, void* d_ws, size_t ws_size,
                              hipStream_t stream)
{
    const float* x      = (const float*)d_in[0];
    const int*   attn   = (const int*)  d_in[1];
    const float* w_attn = (const float*)d_in[2];
    const float* b_attn = (const float*)d_in[3];
    const float* w_proj = (const float*)d_in[4];
    const float* b_proj = (const float*)d_in[5];
    float* out = (float*)d_out;

    // ---- workspace (~210.3 MiB) ----
    char* ws = (char*)d_ws;
    size_t off = 0;
    auto alloc = [&](size_t bytes) { void* p = ws + off; off = (off + bytes + 255) & ~(size_t)255; return p; };
    float* qkv   = (float*)alloc((size_t)16384 * 3072 * 4);   // 192 MiB
    short* waThi = (short*)alloc((size_t)3072 * 1024 * 2);    // 6 MiB (tiled32)
    short* waTlo = (short*)alloc((size_t)3072 * 1024 * 2);    // 6 MiB
    short* wpThi = (short*)alloc((size_t)1024 * 1024 * 2);    // 2 MiB
    short* wpTlo = (short*)alloc((size_t)1024 * 1024 * 2);    // 2 MiB
    float* kvb   = (float*)alloc((size_t)128 * 4096 * 4);     // 2 MiB
    float* ksum  = (float*)alloc((size_t)128 * 64 * 4);       // 32 KiB

    // ---- d_out doubles as scratch before GEMM2 rewrites it ----
    short* xhi = (short*)d_out;                               // 32 MiB (tiled32)
    short* xlo = xhi + (size_t)16384 * 1024;                  // 32 MiB
    float* kvpart = (float*)d_out;                            // 16 MiB (after GEMM1)
    float* kspart = (float*)((char*)d_out + (size_t)128 * 8 * 4096 * 4); // 256 KiB

    // 1) split x -> tiled32 bf16 hi/lo (into d_out)
    split_tile_kernel<<<dim3(512, 16), 256, 0, stream>>>(x, xhi, xlo);
    // 2) transpose+split weights into tiled32 layout (into ws)
    w_tile_kernel<<<1536, 256, 0, stream>>>(w_attn, 3072, waThi, waTlo);  // 6144 tiles
    w_tile_kernel<<<512, 256, 0, stream>>>(w_proj, 1024, wpThi, wpTlo);   // 2048 tiles
    // 3) qkv = x @ w_attn + b_attn  (M=16384,N=3072,K=1024), A+B tiled32
    gemm3_kernel<0><<<dim3(12, 64), 512, 0, stream>>>(xhi, xlo, 0, waThi, waTlo, b_attn, qkv, 1024, 3072);
    // 4) kv partials (into d_out) + reduce (into ws)
    kv_part_kernel<<<dim3(8, 128), 256, 0, stream>>>(qkv, attn, kvpart, kspart);
    kv_reduce_kernel<<<128, 256, 0, stream>>>(kvpart, kspart, kvb, ksum);
    // 5) y -> split bf16, TILED32 into qkv's dead k/v region
    attn_y_kernel<<<dim3(32, 128), 256, 0, stream>>>(qkv, kvb, ksum);
    // 6) out = y @ w_proj + b_proj  (M=16384,N=1024,K=1024); A y-scratch, B tiled32
    gemm3_kernel<2><<<dim3(4, 64), 512, 0, stream>>>((const short*)qkv, (const short*)qkv, 0,
                                                     wpThi, wpTlo, b_proj, out, 1024, 1024);
}

// Round 5
// 570.692 us; speedup vs baseline: 1.0923x; 1.0923x over previous
//
#include <hip/hip_runtime.h>

// (B,T,C,H) = (8,2048,1024,16), D=64
#define Tdim 2048

typedef __attribute__((ext_vector_type(8))) short bf16x8;
typedef __attribute__((ext_vector_type(4))) float f32x4;
typedef __attribute__((ext_vector_type(4))) short short4v;

#define GLOBAL_U32(p) ((const __attribute__((address_space(1))) unsigned int*)(p))
#define LDS_U32(p)    ((__attribute__((address_space(3))) unsigned int*)(p))

// barrier with compiler memory fences (no instruction-order pinning)
#define BARRIER() do { asm volatile("" ::: "memory"); \
                       __builtin_amdgcn_s_barrier(); \
                       asm volatile("" ::: "memory"); } while (0)

__device__ __forceinline__ float phi_f(float x) {
    return x > 0.f ? (x + 1.f) : __expf(x);
}
// round-to-nearest-even fp32 -> bf16 (finite inputs only)
__device__ __forceinline__ short f2bf(float f) {
    unsigned u = __float_as_uint(f);
    u += 0x7fffu + ((u >> 16) & 1u);
    return (short)(u >> 16);
}
__device__ __forceinline__ float bf2f(short h) {
    return __uint_as_float(((unsigned)(unsigned short)h) << 16);
}

// ===========================================================================
// TILED layout: matrix [R x K] bf16 stored as tiles of 16 rows x 32 k.
// Tile (rt, kt) at ((rt*(K/32))+kt)*512 shorts; slot L (0..63) holds
// row rt*16+(L&15), k = kt*32+(L>>4)*8 .. +8.  One wave staging instr = 1 KB
// contiguous; fragment read = tile_base + lane*16B (conflict-free identity).
//
// Y-SCRATCH layout (GEMM2's A): same tile format, but tiles embedded in the
// dead k-region of qkv.  Tile (RT, kt, plane) at physical row RT*16 + hh
// (hh = kt>>1), shorts offset 2048 + ((kt&1)*2 + plane)*512.  Each tile is
// 1 KB contiguous => staging identical to TILED (wave-uniform + lane*16B).
// ===========================================================================

// ---------------------------------------------------------------------------
// x [16384 x 1024] fp32 -> tiled split hi/lo. Block: 16 rows x 128 cols.
// ---------------------------------------------------------------------------
__global__ __launch_bounds__(256) void split_tile_kernel(
    const float* __restrict__ X, short* __restrict__ Hi, short* __restrict__ Lo)
{
    const int rt = blockIdx.x;          // row-tile 0..1023
    const int cb = blockIdx.y;          // col-block 0..7 (128 cols)
    const int t = threadIdx.x;
    const int rl = t >> 4;              // row in tile 0..15
    const int cc = t & 15;              // col-chunk (8 cols) 0..15

    const float* xp = X + ((size_t)rt * 16 + rl) * 1024 + cb * 128 + cc * 8;
    const float4 a = *(const float4*)xp;
    const float4 b = *(const float4*)(xp + 4);
    float v[8] = {a.x, a.y, a.z, a.w, b.x, b.y, b.z, b.w};
    bf16x8 h, l;
#pragma unroll
    for (int j = 0; j < 8; ++j) {
        const short hh = f2bf(v[j]);
        h[j] = hh;
        l[j] = f2bf(v[j] - bf2f(hh));
    }
    const int kt = cb * 4 + (cc >> 2);
    const int slot = ((cc & 3) << 4) | rl;
    const size_t off = ((size_t)rt * 32 + kt) * 512 + slot * 8;
    *(bf16x8*)(Hi + off) = h;
    *(bf16x8*)(Lo + off) = l;
}

// ---------------------------------------------------------------------------
// W [1024 x N] fp32 -> W^T [N x 1024] tiled split hi/lo. One wave per tile.
// nkt = 1024/32 = 32 (hardcoded).
// ---------------------------------------------------------------------------
__global__ __launch_bounds__(256) void w_tile_kernel(
    const float* __restrict__ W, int N,
    short* __restrict__ Thi, short* __restrict__ Tlo)
{
    const int tile = blockIdx.x * 4 + (threadIdx.x >> 6);
    const int nt = tile >> 5;           // n-tile
    const int kt = tile & 31;           // k-tile
    const int lane = threadIdx.x & 63;
    const int n = nt * 16 + (lane & 15);
    const int k = kt * 32 + (lane >> 4) * 8;
    const float* wp = W + (size_t)k * N + n;
    bf16x8 h, l;
#pragma unroll
    for (int j = 0; j < 8; ++j) {
        const float v = wp[(size_t)j * N];
        const short hh = f2bf(v);
        h[j] = hh;
        l[j] = f2bf(v - bf2f(hh));
    }
    const size_t off = (size_t)tile * 512 + lane * 8;
    *(bf16x8*)(Thi + off) = h;
    *(bf16x8*)(Tlo + off) = l;
}

// ---------------------------------------------------------------------------
// bf16x3 split-precision GEMM: C = (Ahi+Alo)[M,K] * (Bhi+Blo)^T[N,K] + bias
// (drops lo*lo).
//
// 256x256 block tile, BK=32, 8 waves (2m x 4n), per-wave output 128x64.
// Double-buffered LDS (2 x 64 KiB).  COUNTED-VMCNT role-split schedule
// (T3+T4): waves 0-3 stage A-planes, waves 4-7 stage B-planes.  Per K-step:
//   P0: B-waves issue next-step loads | all read B(cur) frags |
//       A-waves s_waitcnt vmcnt(0) (their loads are one full compute
//       cluster old -> free) | barrier
//   P1: A-waves issue next-step loads | A-reads + 96 MFMA (setprio) |
//       B-waves vmcnt(0) (covered by the MFMA cluster -> free) | barrier
// No drain of just-issued loads anywhere; no sched_barrier pins (compiler
// keeps its own fine lgkmcnt interleave).  Last iteration re-stages k0=0
// (dummy, never read) to keep per-wave vmcnt counts uniform.
//
// B always TILED.  AMODE 0: A TILED.  AMODE 2: A = y-scratch tiles embedded
// in qkv (see header comment).  Fragment read = identity lane*8.  K = 1024.
// ---------------------------------------------------------------------------
template<int AMODE>
__global__ __launch_bounds__(512, 2) void gemm3_kernel(
    const short* __restrict__ Ahi, const short* __restrict__ Alo, int lda,
    const short* __restrict__ BThi, const short* __restrict__ BTlo,
    const float* __restrict__ bias, float* __restrict__ C,
    int K, int ldc)
{
    // [2 buf][4 arrays][16 tiles][512 shorts] = 128 KiB
    __shared__ short smem[65536];
    const int tid = threadIdx.x;
    const int lane = tid & 63;
    const int wid = tid >> 6;            // wave 0..7
    const int bx = blockIdx.x, by = blockIdx.y;
    const int wm = wid >> 2, wn = wid & 3;

    const size_t tilestep = (size_t)(K >> 5) * 512;   // shorts per row-tile

    // staging: wave w stages 8 tiles of array sel (0:Ahi 1:Alo 2:Bhi 3:Blo),
    // half h (tiles h*8 .. h*8+7).  A-waves = wid 0..3, B-waves = wid 4..7.
    const int sel = wid >> 1, half = wid & 1;
    const bool is_a_wave = (wid < 4);
    const short* gptr;
    if (sel >= 2) {
        const short* gb = (sel == 2) ? BThi : BTlo;
        gptr = gb + (size_t)(bx * 16 + half * 8) * tilestep + lane * 8;
    } else if (AMODE == 0) {
        const short* gb = (sel == 0) ? Ahi : Alo;
        gptr = gb + (size_t)(by * 16 + half * 8) * tilestep + lane * 8;
    } else {
        // AMODE 2: y-scratch tiles in qkv; row-tile RT starts at physical
        // row RT*16; plane offset handled in the k-offset below.
        gptr = Ahi + (size_t)((by * 16 + half * 8) * 16) * 6144 + 2048 + lane * 8;
    }
    // wave-uniform LDS dest base (buffer 0)
    short* lw = smem + sel * 8192 + half * 4096;

    f32x4 acc[8][4];
#pragma unroll
    for (int i = 0; i < 8; ++i)
#pragma unroll
        for (int j = 0; j < 4; ++j) acc[i][j] = (f32x4){0.f, 0.f, 0.f, 0.f};

    auto stage = [&](int buf, int k0) {
        short* lb = lw + buf * 32768;
        if (AMODE == 0 || sel >= 2) {
            const short* g = gptr + (size_t)(k0 >> 5) * 512;
#pragma unroll
            for (int c = 0; c < 8; ++c)
                __builtin_amdgcn_global_load_lds(
                    GLOBAL_U32(g + (size_t)c * tilestep),
                    LDS_U32(lb + c * 512), 16, 0, 0);
        } else {
            // tile (RT, kt=k0>>5, plane=sel): row r = kt>>1 (= head), slot
            // s = (kt&1)*2 + plane; addr = (RT*16 + r)*6144 + 2048 + s*512
            const size_t koff = (size_t)(k0 >> 6) * 6144
                              + (size_t)((((k0 >> 5) & 1) << 1) | sel) * 512;
            const short* g = gptr + koff;
#pragma unroll
            for (int c = 0; c < 8; ++c)
                __builtin_amdgcn_global_load_lds(
                    GLOBAL_U32(g + (size_t)(c * 16) * 6144),
                    LDS_U32(lb + c * 512), 16, 0, 0);
        }
    };

    // prologue: fill buffer 0 completely (full drain + barrier, once)
    stage(0, 0);
    __syncthreads();

    const int fo = lane * 8;
    int cur = 0;
    for (int k0 = 0; k0 < K; k0 += 32) {
        const short* bp = smem + cur * 32768;
        // clamped next-step index: last iter re-stages k0=0 into the
        // never-read buffer (keeps per-wave vmcnt counts uniform)
        const int k0n = (k0 + 32 < K) ? (k0 + 32) : 0;

        // ---- P0: B-wave issue | B-reads | A-wave publish | barrier ----
        if (!is_a_wave) stage(cur ^ 1, k0n);
        bf16x8 bh[4], bl[4];
#pragma unroll
        for (int j = 0; j < 4; ++j) {
            bh[j] = *(const bf16x8*)(bp + 16384 + (wn * 4 + j) * 512 + fo);
            bl[j] = *(const bf16x8*)(bp + 24576 + (wn * 4 + j) * 512 + fo);
        }
        if (is_a_wave) asm volatile("s_waitcnt vmcnt(0)" ::: "memory");
        BARRIER();   // A(cur) now published by all A-waves

        // ---- P1: A-wave issue | A-reads + MFMA | B-wave publish | barrier --
        if (is_a_wave) stage(cur ^ 1, k0n);
        __builtin_amdgcn_s_setprio(1);
#pragma unroll
        for (int i = 0; i < 8; ++i) {
            const bf16x8 ah = *(const bf16x8*)(bp + (wm * 8 + i) * 512 + fo);
            const bf16x8 al = *(const bf16x8*)(bp + 8192 + (wm * 8 + i) * 512 + fo);
#pragma unroll
            for (int j = 0; j < 4; ++j) {
                acc[i][j] = __builtin_amdgcn_mfma_f32_16x16x32_bf16(ah, bh[j], acc[i][j], 0, 0, 0);
                acc[i][j] = __builtin_amdgcn_mfma_f32_16x16x32_bf16(al, bh[j], acc[i][j], 0, 0, 0);
                acc[i][j] = __builtin_amdgcn_mfma_f32_16x16x32_bf16(ah, bl[j], acc[i][j], 0, 0, 0);
            }
        }
        __builtin_amdgcn_s_setprio(0);
        if (!is_a_wave) asm volatile("s_waitcnt vmcnt(0)" ::: "memory");
        BARRIER();   // B(next) published; buf cur fully consumed
        cur ^= 1;
    }

    // epilogue: C/D layout col=lane&15, row=(lane>>4)*4+reg
    const int fr = lane & 15, fq = lane >> 4;
#pragma unroll
    for (int i = 0; i < 8; ++i) {
        const size_t row0 = (size_t)by * 256 + wm * 128 + i * 16 + fq * 4;
#pragma unroll
        for (int j = 0; j < 4; ++j) {
            const int col = bx * 256 + wn * 64 + j * 16 + fr;
            const float bv = bias[col];
            float* cp = C + row0 * (size_t)ldc + col;
#pragma unroll
            for (int r = 0; r < 4; ++r)
                cp[(size_t)r * ldc] = acc[i][j][r] + bv;
        }
    }
}

// ---------------------------------------------------------------------------
// Partial kv/ksum per (T-chunk, bh): 8 x 128 = 1024 blocks.
// ---------------------------------------------------------------------------
__global__ __launch_bounds__(256) void kv_part_kernel(
    const float* __restrict__ qkv, const int* __restrict__ attn,
    float* __restrict__ kvpart, float* __restrict__ kspart)
{
    __shared__ float ks[32][64];
    __shared__ float vs[32][64];

    const int chunk = blockIdx.x;       // 0..7
    const int bh = blockIdx.y;          // 0..127
    const int b = bh >> 4;
    const int h = bh & 15;
    const int tid = threadIdx.x;
    const int tx = tid & 15;
    const int ty = tid >> 4;
    const int l_t = tid >> 4;
    const int l_d = (tid & 15) << 2;

    const float* kb = qkv + (size_t)b * Tdim * 3072 + 1024 + h * 64;
    const float* vb = qkv + (size_t)b * Tdim * 3072 + 2048 + h * 64;
    const int* am = attn + b * Tdim;

    float acc[4][4];
#pragma unroll
    for (int i = 0; i < 4; ++i)
#pragma unroll
        for (int j = 0; j < 4; ++j) acc[i][j] = 0.f;
    float ksl = 0.f;

    for (int t0 = chunk * 256; t0 < (chunk + 1) * 256; t0 += 32) {
        __syncthreads();
#pragma unroll
        for (int rr = 0; rr < 2; ++rr) {
            const int t = l_t + rr * 16;
            const int gt = t0 + t;
            const float m = (am[gt] > 0) ? 1.f : 0.f;
            const float4 k4 = *(const float4*)(kb + (size_t)gt * 3072 + l_d);
            const float4 v4 = *(const float4*)(vb + (size_t)gt * 3072 + l_d);
            float4 kp, vp;
            kp.x = phi_f(k4.x) * m; kp.y = phi_f(k4.y) * m;
            kp.z = phi_f(k4.z) * m; kp.w = phi_f(k4.w) * m;
            vp.x = v4.x * m; vp.y = v4.y * m; vp.z = v4.z * m; vp.w = v4.w * m;
            *(float4*)&ks[t][l_d] = kp;
            *(float4*)&vs[t][l_d] = vp;
        }
        __syncthreads();
#pragma unroll
        for (int t = 0; t < 32; ++t) {
            float kr[4], vr[4];
            *(float4*)kr = *(const float4*)&ks[t][ty * 4];
            *(float4*)vr = *(const float4*)&vs[t][tx * 4];
#pragma unroll
            for (int i = 0; i < 4; ++i)
#pragma unroll
                for (int j = 0; j < 4; ++j)
                    acc[i][j] = fmaf(kr[i], vr[j], acc[i][j]);
        }
        if (tid < 64) {
#pragma unroll
            for (int t = 0; t < 32; ++t) ksl += ks[t][tid];
        }
    }

    float* ko = kvpart + ((size_t)bh * 8 + chunk) * 4096;
#pragma unroll
    for (int i = 0; i < 4; ++i) {
        float4 o;
        o.x = acc[i][0]; o.y = acc[i][1]; o.z = acc[i][2]; o.w = acc[i][3];
        *(float4*)(ko + (ty * 4 + i) * 64 + tx * 4) = o;
    }
    if (tid < 64) kspart[((size_t)bh * 8 + chunk) * 64 + tid] = ksl;
}

__global__ __launch_bounds__(256) void kv_reduce_kernel(
    const float* __restrict__ kvpart, const float* __restrict__ kspart,
    float* __restrict__ kv, float* __restrict__ ksum)
{
    const int bh = blockIdx.x;
    const int tid = threadIdx.x;
    const float4* p = (const float4*)(kvpart + (size_t)bh * 8 * 4096);
    float4 s0 = {0,0,0,0}, s1 = {0,0,0,0}, s2 = {0,0,0,0}, s3 = {0,0,0,0};
#pragma unroll
    for (int c = 0; c < 8; ++c) {
        const int base = c * 1024;
        float4 a = p[base + tid], b = p[base + 256 + tid],
               cc = p[base + 512 + tid], d = p[base + 768 + tid];
        s0.x += a.x; s0.y += a.y; s0.z += a.z; s0.w += a.w;
        s1.x += b.x; s1.y += b.y; s1.z += b.z; s1.w += b.w;
        s2.x += cc.x; s2.y += cc.y; s2.z += cc.z; s2.w += cc.w;
        s3.x += d.x; s3.y += d.y; s3.z += d.z; s3.w += d.w;
    }
    float4* o = (float4*)(kv + (size_t)bh * 4096);
    o[tid] = s0; o[256 + tid] = s1; o[512 + tid] = s2; o[768 + tid] = s3;
    if (tid < 64) {
        float ss = 0.f;
#pragma unroll
        for (int c = 0; c < 8; ++c) ss += kspart[((size_t)bh * 8 + c) * 64 + tid];
        ksum[bh * 64 + tid] = ss;
    }
}

// ---------------------------------------------------------------------------
// y[t][f] = (phi(q[t])·kv[:,f]) / max(phi(q[t])·ksum, 1e-8).
// Writes y split hi/lo bf16 in TILED format into the dead k-region of qkv:
// tile (RT, kt=hh*2+kl, plane p) lives at physical row RT*16+hh, shorts
// offset 2048 + (kl*2+p)*512 (1 KB contiguous tile).  The q columns this
// kernel still reads ([0..1024) floats) are never touched; k/v are dead
// after kv_part.  Disjoint (row, slot) across heads -> no races.
// ---------------------------------------------------------------------------
__global__ __launch_bounds__(256) void attn_y_kernel(
    float* __restrict__ qkv, const float* __restrict__ kvin,
    const float* __restrict__ ksumin)
{
    __shared__ float qs[64][65];
    __shared__ float kvs[64][64];
    __shared__ float dinv[64];
    __shared__ float ksums[64];

    const int bh = blockIdx.y;
    const int b = bh >> 4;
    const int hh = bh & 15;
    const int t0 = blockIdx.x * 64;
    const int tid = threadIdx.x;
    const int tx = tid & 15;
    const int ty = tid >> 4;

    const float4* kvg = (const float4*)(kvin + (size_t)bh * 4096);
#pragma unroll
    for (int i = 0; i < 4; ++i)
        ((float4*)kvs)[tid + i * 256] = kvg[tid + i * 256];
    if (tid < 64) ksums[tid] = ksumin[bh * 64 + tid];

    float* qb = qkv + ((size_t)(b * Tdim + t0)) * 3072 + hh * 64;
#pragma unroll
    for (int rr = 0; rr < 4; ++rr) {
        const int t = (tid >> 4) + rr * 16;
        const int dd = (tid & 15) << 2;
        const float4 q4 = *(const float4*)(qb + (size_t)t * 3072 + dd);
        qs[t][dd + 0] = phi_f(q4.x);
        qs[t][dd + 1] = phi_f(q4.y);
        qs[t][dd + 2] = phi_f(q4.z);
        qs[t][dd + 3] = phi_f(q4.w);
    }
    __syncthreads();

    if (tid < 64) {
        float s = 0.f;
#pragma unroll
        for (int d = 0; d < 64; ++d) s = fmaf(qs[tid][d], ksums[d], s);
        dinv[tid] = 1.f / fmaxf(s, 1e-8f);
    }
    __syncthreads();

    float acc[4][4];
#pragma unroll
    for (int i = 0; i < 4; ++i)
#pragma unroll
        for (int j = 0; j < 4; ++j) acc[i][j] = 0.f;

#pragma unroll 4
    for (int d = 0; d < 64; ++d) {
        float qr[4];
        qr[0] = qs[ty * 4 + 0][d];
        qr[1] = qs[ty * 4 + 1][d];
        qr[2] = qs[ty * 4 + 2][d];
        qr[3] = qs[ty * 4 + 3][d];
        const float4 kr = *(const float4*)&kvs[d][tx * 4];
#pragma unroll
        for (int i = 0; i < 4; ++i) {
            acc[i][0] = fmaf(qr[i], kr.x, acc[i][0]);
            acc[i][1] = fmaf(qr[i], kr.y, acc[i][1]);
            acc[i][2] = fmaf(qr[i], kr.z, acc[i][2]);
            acc[i][3] = fmaf(qr[i], kr.w, acc[i][3]);
        }
    }

    // ---- tiled y-scratch write ----
    // thread covers rows t=ty*4+i (local 0..63), cols d=tx*4+j (0..63).
    // kl = d>>5; within-tile k = d&31 -> slot L = ((k>>3)<<4)|(t&15),
    // within-slot offset (d&7) = (tx&1)*4.
    short* yb = (short*)qkv;
    const int kl = tx >> 3;            // k-tile within head (0/1)
    const int chunk = (tx & 7) >> 1;   // k-chunk within tile (0..3)
    const int h4 = (tx & 1) * 4;       // offset within 8-short chunk
    const int gb2 = b * Tdim;          // global row base of this batch
#pragma unroll
    for (int i = 0; i < 4; ++i) {
        const int t = ty * 4 + i;
        const int RT = ((gb2 + t0) >> 4) + (t >> 4);
        const float di = dinv[t];
        short4v hv, lv;
#pragma unroll
        for (int j = 0; j < 4; ++j) {
            const float val = acc[i][j] * di;
            const short h = f2bf(val);
            hv[j] = h;
            lv[j] = f2bf(val - bf2f(h));
        }
        const size_t tb = (size_t)(RT * 16 + hh) * 6144 + 2048
                        + (size_t)(kl * 2) * 512
                        + (((chunk << 4) | (t & 15)) * 8 + h4);
        *(short4v*)(yb + tb) = hv;            // plane 0 (hi)
        *(short4v*)(yb + tb + 512) = lv;      // plane 1 (lo)
    }
}

// ---------------------------------------------------------------------------
extern "C" void kernel_launch(void* const* d_in, const int* in_sizes, int n_in,
                              void* d_out, int out_size, void* d_ws, size_t ws_size,
                              hipStream_t stream)
{
    const float* x      = (const float*)d_in[0];
    const int*   attn   = (const int*)  d_in[1];
    const float* w_attn = (const float*)d_in[2];
    const float* b_attn = (const float*)d_in[3];
    const float* w_proj = (const float*)d_in[4];
    const float* b_proj = (const float*)d_in[5];
    float* out = (float*)d_out;

    // ---- workspace (~210.3 MiB) ----
    char* ws = (char*)d_ws;
    size_t off = 0;
    auto alloc = [&](size_t bytes) { void* p = ws + off; off = (off + bytes + 255) & ~(size_t)255; return p; };
    float* qkv   = (float*)alloc((size_t)16384 * 3072 * 4);   // 192 MiB
    short* waThi = (short*)alloc((size_t)3072 * 1024 * 2);    // 6 MiB (tiled)
    short* waTlo = (short*)alloc((size_t)3072 * 1024 * 2);    // 6 MiB
    short* wpThi = (short*)alloc((size_t)1024 * 1024 * 2);    // 2 MiB
    short* wpTlo = (short*)alloc((size_t)1024 * 1024 * 2);    // 2 MiB
    float* kvb   = (float*)alloc((size_t)128 * 4096 * 4);     // 2 MiB
    float* ksum  = (float*)alloc((size_t)128 * 64 * 4);       // 32 KiB

    // ---- d_out doubles as scratch before GEMM2 rewrites it ----
    short* xhi = (short*)d_out;                               // 32 MiB (tiled)
    short* xlo = xhi + (size_t)16384 * 1024;                  // 32 MiB
    float* kvpart = (float*)d_out;                            // 16 MiB (after GEMM1)
    float* kspart = (float*)((char*)d_out + (size_t)128 * 8 * 4096 * 4); // 256 KiB

    // 1) split x -> tiled bf16 hi/lo (into d_out)
    split_tile_kernel<<<dim3(1024, 8), 256, 0, stream>>>(x, xhi, xlo);
    // 2) transpose+split weights into tiled layout (into ws)
    w_tile_kernel<<<1536, 256, 0, stream>>>(w_attn, 3072, waThi, waTlo);  // 6144 tiles
    w_tile_kernel<<<512, 256, 0, stream>>>(w_proj, 1024, wpThi, wpTlo);   // 2048 tiles
    // 3) qkv = x @ w_attn + b_attn  (M=16384,N=3072,K=1024), A+B tiled
    gemm3_kernel<0><<<dim3(12, 64), 512, 0, stream>>>(xhi, xlo, 0, waThi, waTlo, b_attn, qkv, 1024, 3072);
    // 4) kv partials (into d_out) + reduce (into ws)
    kv_part_kernel<<<dim3(8, 128), 256, 0, stream>>>(qkv, attn, kvpart, kspart);
    kv_reduce_kernel<<<128, 256, 0, stream>>>(kvpart, kspart, kvb, ksum);
    // 5) y -> split bf16, TILED into qkv's dead k-region
    attn_y_kernel<<<dim3(32, 128), 256, 0, stream>>>(qkv, kvb, ksum);
    // 6) out = y @ w_proj + b_proj  (M=16384,N=1024,K=1024); A y-scratch tiled, B tiled
    gemm3_kernel<2><<<dim3(4, 64), 512, 0, stream>>>((const short*)qkv, (const short*)qkv, 0,
                                                     wpThi, wpTlo, b_proj, out, 1024, 1024);
}